// Round 11
// baseline (174.526 us; speedup 1.0000x reference)
//
#include <hip/hip_runtime.h>
#include <hip/hip_bf16.h>
#include <math.h>

typedef unsigned short u16;
typedef unsigned char u8;
typedef unsigned int u32;
typedef long long i64;
typedef __attribute__((ext_vector_type(16))) float f32x16;

// -------------------------------------------------- fp32 -> fp8 e4m3 (x16 pre-scale)
// l2-normed inputs: |x| <~ 0.3 -> x*16 in [~0.01, 4.8]: full mantissa, no saturation.
// Dequant folded into gemm epilogue (divide by 256*temp).
//
// K-PERMUTED OUTPUT for 32x32x16 fragments: within each 128-byte K-block of a
// row, global byte (16s + 8h + b) [s=0..7 K-step, h=0..1 lane-half, b=0..7] is
// stored at (64h + 8s + b). Same permutation on A and B -> dots unchanged
// (R9/R10-verified technique). A lane-half's operands for steps 2t,2t+1 are
// then one contiguous 16B chunk (c = 4h + t).
__global__ void cvt_fused(const float* __restrict__ F, const float* __restrict__ T,
                          u32* __restrict__ Fb, u32* __restrict__ Tb,
                          float* __restrict__ out) {
    const int idx = blockIdx.x * blockDim.x + threadIdx.x;
    if (idx == 0) out[0] = 0.f;
    const float* s;
    u32* d;
    int i;
    if (idx < 65536) { s = F; d = Fb; i = idx; }
    else             { s = T; d = Tb; i = idx - 65536; }
    const float4 v0 = *(const float4*)(s + (size_t)i * 8);
    const float4 v1 = *(const float4*)(s + (size_t)i * 8 + 4);
    int lo = __builtin_amdgcn_cvt_pk_fp8_f32(v0.x * 16.f, v0.y * 16.f, 0, false);
    lo     = __builtin_amdgcn_cvt_pk_fp8_f32(v0.z * 16.f, v0.w * 16.f, lo, true);
    int hi = __builtin_amdgcn_cvt_pk_fp8_f32(v1.x * 16.f, v1.y * 16.f, 0, false);
    hi     = __builtin_amdgcn_cvt_pk_fp8_f32(v1.z * 16.f, v1.w * 16.f, hi, true);
    uint2 o; o.x = (u32)lo; o.y = (u32)hi;
    // one uint2 = 8 B = exactly one (s,h) group of one 128-B block
    const int r  = i >> 6;            // row (512 B = 64 uint2)
    const int l6 = i & 63;
    const int t  = (l6 >> 4) & 3;     // 128-B block
    const int ss = (l6 >> 1) & 7;     // K-step within block
    const int h  = l6 & 1;            // lane-half
    d[(r << 6) + (t << 4) + (h << 3) + ss] = 0, ((uint2*)d)[(r << 6) + (t << 4) + (h << 3) + ss] = o;
}

// ---------------------------------------------------------------- GEMM + max
#define GLB_AS __attribute__((address_space(1)))
#define LDS_AS __attribute__((address_space(3)))

__device__ __forceinline__ void gload_lds16(const void* g, void* l) {
    __builtin_amdgcn_global_load_lds((const GLB_AS void*)g, (LDS_AS void*)l, 16, 0, 0);
}

__device__ __forceinline__ i64 half0(int4 v) { int2 p; p.x = v.x; p.y = v.y; return __builtin_bit_cast(i64, p); }
__device__ __forceinline__ i64 half1(int4 v) { int2 p; p.x = v.z; p.y = v.w; return __builtin_bit_cast(i64, p); }

// A: F fp8 [1024 x 512], B: T fp8 [32768 x 512] (row-major, K-permuted per cvt).
// sim[i*1024+j] = max_{q<32} dot(A[i],B[j*32+q]) / (256*temp)
//
// R11: 64x64 WAVE TILE with mfma_f32_32x32x16_fp8_fp8 (2-reg operands).
// R4..R10 all sat at ~43-48 us under additive pipe floors (MFMA 16.6 + LDS 15
// + VALU 11 us); the LDS-read/FLOP ratio is set by the wave tile, so grow it:
// 32x64 -> 64x64 gives 64 FLOP/LDS-byte (805 -> 537 MB) and 32x32 shape halves
// MFMA instr count (issue slots) at the same rate (2382 TF -> 14.4 us floor).
// acc 4xf32x16=64 + int4 frags 16 + addr ~25 ≈ 105 regs < 128 cap -> (256,4),
// 32 KB LDS single-buffer, 4 blocks/CU (light operands; R6/R8's spills came
// from mfma_scale's 8-reg operands, avoided here).
// LDS: rows of 128 B in 8-row groups; 16B chunk c of row r at slot c^(r&7)
// (R4/R9-verified conflict-free); frag chunk c = 4h + t.
__global__ __launch_bounds__(256, 4)
void gemm_max(const u8* __restrict__ A, const u8* __restrict__ B,
              const float* __restrict__ temp_ptr, float* __restrict__ sim) {
    __shared__ __align__(16) u8 lA[128 * 128];   // 16 KB
    __shared__ __align__(16) u8 lB[128 * 128];   // 16 KB
    const int bn = blockIdx.x;      // 0..255 (N tiles of 128 B-rows = 4 j's)
    const int bm = blockIdx.y;      // 0..7   (M tiles of 128)
    const int tid  = threadIdx.x;
    const int wave = tid >> 6;
    const int lane = tid & 63;
    const int wm = wave >> 1;       // 0..1: rows wm*64
    const int wn = wave & 1;        // 0..1: cols wn*64

    f32x16 acc[2][2] = {};

    // staging: one glds = 8 rows x 128B. lane -> srow = lane>>3; slot lane&7
    // holds global chunk (lane&7)^srow.
    const int srow = lane >> 3;
    const int aoff = srow * 512 + (((lane & 7) ^ srow) << 4);
    const u8* gA = A + (size_t)(bm * 128) * 512 + aoff;
    const u8* gB = B + (size_t)(bn * 128) * 512 + aoff;

    const int l31 = lane & 31;
    const int h   = lane >> 5;
    const int r7  = l31 & 7;        // row&7 (row offsets are multiples of 32)
    const int gquad = l31 >> 3;     // row's position within its 8-row group

    for (int k0 = 0; k0 < 512; k0 += 128) {
#pragma unroll
        for (int j = 0; j < 4; ++j) {           // 16 groups of 8 rows, 4 per wave
            gload_lds16(gA + (wave + 4 * j) * 4096 + k0, lA + (wave + 4 * j) * 1024);
            gload_lds16(gB + (wave + 4 * j) * 4096 + k0, lB + (wave + 4 * j) * 1024);
        }
        __syncthreads();

#pragma unroll
        for (int t = 0; t < 4; ++t) {           // each t = K-steps 2t, 2t+1
            const int csw = ((((h << 2) + t) ^ r7) << 4) + (r7 << 7);
            int4 aF[2], bF[2];
#pragma unroll
            for (int mt = 0; mt < 2; ++mt)
                aF[mt] = *(const int4*)&lA[((wm * 8 + mt * 4 + gquad) << 10) + csw];
#pragma unroll
            for (int nt = 0; nt < 2; ++nt)
                bF[nt] = *(const int4*)&lB[((wn * 8 + nt * 4 + gquad) << 10) + csw];
#pragma unroll
            for (int mt = 0; mt < 2; ++mt)
#pragma unroll
                for (int nt = 0; nt < 2; ++nt) {
                    acc[mt][nt] = __builtin_amdgcn_mfma_f32_32x32x16_fp8_fp8(
                        half0(aF[mt]), half0(bF[nt]), acc[mt][nt], 0, 0, 0);
                    acc[mt][nt] = __builtin_amdgcn_mfma_f32_32x32x16_fp8_fp8(
                        half1(aF[mt]), half1(bF[nt]), acc[mt][nt], 0, 0, 0);
                }
        }
        __syncthreads();
    }

    // epilogue: acc[mt][nt] is the 32x32 C tile at rows bm*128+wm*64+mt*32,
    // cols bn*128+wn*64+nt*32 — exactly one j per acc.
    // C/D layout (verified m74/m101): col = lane&31, row = (reg&3)+8*(reg>>2)+4*h.
    const float inv = 1.0f / (256.0f * (*temp_ptr));
#pragma unroll
    for (int mt = 0; mt < 2; ++mt) {
#pragma unroll
        for (int nt = 0; nt < 2; ++nt) {
            const int j = bn * 4 + wn * 2 + nt;
#pragma unroll
            for (int reg = 0; reg < 16; ++reg) {
                float v = acc[mt][nt][reg];
#pragma unroll
                for (int off = 1; off <= 16; off <<= 1)
                    v = fmaxf(v, __shfl_xor(v, off));   // max over cols (within half)
                if (l31 == 0) {
                    const int row = bm * 128 + wm * 64 + mt * 32
                                  + (reg & 3) + 8 * (reg >> 2) + 4 * h;
                    sim[row * 1024 + j] = v * inv;
                }
            }
        }
    }
}

// ---------------------------------------------------------------- per-row loss
// ONE WAVE PER ROW, zero LDS, zero barriers. Row (1024 fp32) in 16 regs/lane.
__device__ __forceinline__ u32 f2key(float x) {
    u32 b = __float_as_uint(x);
    return (b & 0x80000000u) ? ~b : (b | 0x80000000u);
}
__device__ __forceinline__ float key2f(u32 k) {
    return __uint_as_float((k & 0x80000000u) ? (k & 0x7fffffffu) : ~k);
}

__global__ __launch_bounds__(256)
void row_loss(const float* __restrict__ sim, float* __restrict__ out) {
    const int tid = threadIdx.x;
    const int lane = tid & 63;
    const int wv = tid >> 6;
    const int i = blockIdx.x * 4 + wv;          // row index

    float v[16];
    const float4* rp = (const float4*)(sim + (size_t)i * 1024);
#pragma unroll
    for (int t = 0; t < 4; ++t) {
        float4 f = rp[t * 64 + lane];
        v[t * 4 + 0] = f.x; v[t * 4 + 1] = f.y; v[t * 4 + 2] = f.z; v[t * 4 + 3] = f.w;
    }

    const int dslot = ((i >> 8) << 2) | (i & 3);
    const int dlane = (i >> 2) & 63;

    u32 k[16];
#pragma unroll
    for (int t = 0; t < 16; ++t) {
        u32 kk = f2key(v[t]);
        k[t] = (lane == dlane && t == dslot) ? 0u : kk;   // diag -> below any finite key
    }

    float pv = 0.f;
#pragma unroll
    for (int t = 0; t < 16; ++t) if (t == dslot) pv = v[t];
    const float pos = __shfl(pv, dlane);

    float m = v[0];
#pragma unroll
    for (int t = 1; t < 16; ++t) m = fmaxf(m, v[t]);
#pragma unroll
    for (int off = 32; off > 0; off >>= 1) m = fmaxf(m, __shfl_xor(m, off));
    float s = 0.f;
#pragma unroll
    for (int t = 0; t < 16; ++t) s += __expf(v[t] - m);
#pragma unroll
    for (int off = 32; off > 0; off >>= 1) s += __shfl_xor(s, off);
    const float loss_std = m + __logf(s) - pos;

    // binary search: largest x with count(key >= x) >= 512
    u32 lo = 0u, hi = 0xFFFFFFFFu;
    while (lo < hi) {
        const u32 span = hi - lo;
        const u32 mid = lo + (span >> 1) + (span & 1u);
        int cnt = 0;
#pragma unroll
        for (int t = 0; t < 16; ++t) cnt += (k[t] >= mid);
#pragma unroll
        for (int off = 32; off > 0; off >>= 1) cnt += __shfl_xor(cnt, off);
        if (cnt >= 512) lo = mid; else hi = mid - 1;
    }
    const u32 t_key = lo;
    const float tval = key2f(t_key);

    float se = 0.f;
    int cgt = 0;
#pragma unroll
    for (int t = 0; t < 16; ++t) {
        if (k[t] > t_key) { se += __expf(v[t] - m); ++cgt; }
    }
#pragma unroll
    for (int off = 32; off > 0; off >>= 1) se += __shfl_xor(se, off);
#pragma unroll
    for (int off = 32; off > 0; off >>= 1) cgt += __shfl_xor(cgt, off);

    const float sh = se + (float)(512 - cgt) * __expf(tval - m) + __expf(pos - m);
    const float hard = m + __logf(sh) - pos;

    if (lane == 0)
        atomicAdd(out, (loss_std + 0.5f * hard) * (1.0f / 1024.0f));
}

// ---------------------------------------------------------------- launch
extern "C" void kernel_launch(void* const* d_in, const int* in_sizes, int n_in,
                              void* d_out, int out_size, void* d_ws, size_t ws_size,
                              hipStream_t stream) {
    const float* F    = (const float*)d_in[0];   // 1024*512
    const float* T    = (const float*)d_in[1];   // 1024*32*512
    const float* temp = (const float*)d_in[2];   // scalar
    float* out = (float*)d_out;

    char* ws = (char*)d_ws;
    u32*  Fb8 = (u32*)ws;                                   // 0.5 MB fp8
    u32*  Tb8 = (u32*)(ws + (1u << 20));                    // 16 MB fp8
    float* sim = (float*)(ws + (1u << 20) + (32u << 20));   // 4 MB

    cvt_fused<<<8448, 256, 0, stream>>>(F, T, Fb8, Tb8, out);

    dim3 grid(256, 8);
    gemm_max<<<grid, 256, 0, stream>>>((const u8*)Fb8, (const u8*)Tb8, temp, sim);

    row_loss<<<256, 256, 0, stream>>>(sim, out);
}